// Round 4
// baseline (270.070 us; speedup 1.0000x reference)
//
#include <hip/hip_runtime.h>
#include <hip/hip_bf16.h>

#define N_Q   16384
#define MCTX  4096
#define DSIN  256
#define YDIM  7
#define PDIM  256   // SPROJ
#define BK    32

typedef __attribute__((ext_vector_type(8))) short s16x8;   // 8 bf16 (4 VGPRs)
typedef __attribute__((ext_vector_type(4))) float f32x4;   // MFMA C/D frag
typedef unsigned short u16;

static __device__ __forceinline__ u16 f2bf(float f) {
    union { float f; unsigned u; } v; v.f = f;
    unsigned r = v.u + 0x7fffu + ((v.u >> 16) & 1u);  // RNE
    return (u16)(r >> 16);
}
static __device__ __forceinline__ float bf2f(u16 h) {
    union { unsigned u; float f; } v; v.u = ((unsigned)h) << 16;
    return v.f;
}
static __device__ __forceinline__ unsigned pack2bf(float lo, float hi) {
    return ((unsigned)f2bf(hi) << 16) | (unsigned)f2bf(lo);
}
static __device__ __forceinline__ f32x4 mfma16(s16x8 a, s16x8 b, f32x4 c) {
    return __builtin_amdgcn_mfma_f32_16x16x32_bf16(a, b, c, 0, 0, 0);
}
// async 16B global->LDS DMA (dst = wave-uniform base + lane*16)
static __device__ __forceinline__ void gload_lds16(const u16* g, u16* l) {
    __builtin_amdgcn_global_load_lds(
        (const __attribute__((address_space(1))) unsigned int*)(g),
        (__attribute__((address_space(3))) unsigned int*)(l), 16, 0, 0);
}

// ---------------- K_prep: (a) Wq transpose + hi/lo split, (b) YK + transposed Vt ----
__global__ void k_prep(const float* __restrict__ Wq, u16* __restrict__ WtH,
                       u16* __restrict__ WtL, const float* __restrict__ y,
                       const float* __restrict__ Wk, const float* __restrict__ Wv,
                       u16* __restrict__ YK, u16* __restrict__ YVt) {
    if (blockIdx.x < PDIM) {
        int n = blockIdx.x;   // 0..PDIM-1
        int k = threadIdx.x;  // 0..DSIN-1
        float w = Wq[(size_t)k * PDIM + n];
        u16 h = f2bf(w);
        WtH[(size_t)n * DSIN + k] = h;
        WtL[(size_t)n * DSIN + k] = f2bf(w - bf2f(h));
    } else {
        // YK scaled 1/16 row-major [key][p]; Vt transposed [p][key]
        int kb = blockIdx.x - PDIM;  // key block (32 keys)
        int p  = threadIdx.x;        // proj
        float wk[YDIM], wv[YDIM];
#pragma unroll
        for (int j = 0; j < YDIM; ++j) {
            wk[j] = Wk[(size_t)j * PDIM + p];
            wv[j] = Wv[(size_t)j * PDIM + p];
        }
        u16 vbuf[32];
#pragma unroll
        for (int m = 0; m < 32; ++m) {
            int key = kb * 32 + m;
            float ak = 0.f, av = 0.f;
#pragma unroll
            for (int j = 0; j < YDIM; ++j) {
                float yy = y[(size_t)key * YDIM + j];
                ak += yy * wk[j];
                av += yy * wv[j];
            }
            YK[(size_t)key * PDIM + p] = f2bf(ak * 0.0625f);  // fold 1/sqrt(256)
            vbuf[m] = f2bf(av);
        }
        s16x8* dst = (s16x8*)(YVt + (size_t)p * MCTX + kb * 32);
#pragma unroll
        for (int c = 0; c < 4; ++c) dst[c] = ((s16x8*)vbuf)[c];
    }
}

// ---------------- K1: XQ = x @ Wq, hi/lo split (unchanged, small) ----------------
__global__ __launch_bounds__(256, 2) void k_xq(const float* __restrict__ x,
                                               const u16* __restrict__ WtH,
                                               const u16* __restrict__ WtL,
                                               u16* __restrict__ XQ) {
    __shared__ u16 xH[32 * 256];  // XOR-swizzled 16B chunks: phys c = c ^ (row&7)
    __shared__ u16 xL[32 * 256];
    const int tid = threadIdx.x;
    const int rowg0 = blockIdx.x * 32;
#pragma unroll
    for (int i = 0; i < 4; ++i) {
        int row = (tid >> 5) + i * 8;
        int c32 = tid & 31;
        const float* px = x + (size_t)(rowg0 + row) * DSIN + c32 * 8;
        float4 a = *(const float4*)px;
        float4 b = *(const float4*)(px + 4);
        float vals[8] = {a.x, a.y, a.z, a.w, b.x, b.y, b.z, b.w};
        s16x8 h, l;
#pragma unroll
        for (int j = 0; j < 8; ++j) {
            u16 hh = f2bf(vals[j]);
            h[j] = (short)hh;
            l[j] = (short)f2bf(vals[j] - bf2f(hh));
        }
        int pc = c32 ^ (row & 7);
        *(s16x8*)(xH + row * 256 + pc * 8) = h;
        *(s16x8*)(xL + row * 256 + pc * 8) = l;
    }
    __syncthreads();

    const int wave = tid >> 6, lane = tid & 63;
    const int quad = lane >> 4, m16 = lane & 15;
    const int rh = wave & 1, ph = wave >> 1;
    const int rowl = rh * 16 + m16;
    const int swz = rowl & 7;
    s16x8 ah[8], al[8];
#pragma unroll
    for (int kf = 0; kf < 8; ++kf) {
        int pc = (kf * 4 + quad) ^ swz;
        ah[kf] = *(const s16x8*)(xH + rowl * 256 + pc * 8);
        al[kf] = *(const s16x8*)(xL + rowl * 256 + pc * 8);
    }
#pragma unroll
    for (int ptl = 0; ptl < 8; ++ptl) {
        int pt = ph * 8 + ptl;
        f32x4 acc = (f32x4){0.f, 0.f, 0.f, 0.f};
#pragma unroll
        for (int kf = 0; kf < 8; ++kf) {
            size_t idx = (size_t)(pt * 16 + m16) * DSIN + kf * 32 + quad * 8;
            s16x8 bh = *(const s16x8*)(WtH + idx);
            s16x8 bl = *(const s16x8*)(WtL + idx);
            acc = mfma16(ah[kf], bh, acc);
            acc = mfma16(al[kf], bh, acc);
            acc = mfma16(ah[kf], bl, acc);
        }
#pragma unroll
        for (int r = 0; r < 4; ++r)
            XQ[(size_t)(rowg0 + rh * 16 + quad * 4 + r) * PDIM + pt * 16 + m16] =
                f2bf(acc[r]);
    }
}

// ---------------- K2: pass A — QK only, row sums L (exp) and Rs (relu) ----------------
// Swapped QK: mfma(A=K, B=Q) -> lane holds S[key=quad*4+r / 16+quad*4+r][q=m16].
// Per-lane accumulate over iters; reduce across quads (xor16/xor32) at the end.
__global__ __launch_bounds__(256, 4) void k_lr(const u16* __restrict__ XQ,
                                               const u16* __restrict__ YK,
                                               float* __restrict__ Lp,
                                               float* __restrict__ Rp,
                                               int msPerSplit) {
    __shared__ u16 Kt[2][32 * 256];  // 32 keys x 256 d, XOR-swizzled chunks, dbuf

    const int tid = threadIdx.x;
    const int wave = tid >> 6, lane = tid & 63;
    const int quad = lane >> 4, m16 = lane & 15;
    const int split = blockIdx.y;
    const int qbase = blockIdx.x * 64;
    const int key_begin = split * msPerSplit;
    const int iters = msPerSplit / BK;
    const int swz = m16 & 7;

    s16x8 qf[8];
    const u16* qp = XQ + (size_t)(qbase + wave * 16 + m16) * DSIN;
#pragma unroll
    for (int kf = 0; kf < 8; ++kf)
        qf[kf] = *(const s16x8*)(qp + kf * 32 + quad * 8);

    auto stage = [&](int key0, int buf) {
#pragma unroll
        for (int c = 0; c < 4; ++c) {
            int l = (wave * 4 + c) * 64 + lane;   // phys chunk
            int r = l >> 5;
            int sc = (l & 31) ^ (r & 7);
            gload_lds16(YK + (size_t)(key0 + r) * DSIN + sc * 8,
                        &Kt[buf][(size_t)(wave * 4 + c) * 512]);
        }
    };
    stage(key_begin, 0);

    float lacc = 0.f, racc = 0.f;
    for (int it = 0; it < iters; ++it) {
        const int cur = it & 1;
        __syncthreads();   // DMA(cur) landed; prev reads of buf cur^1 done
        if (it + 1 < iters) stage(key_begin + (it + 1) * BK, cur ^ 1);

        f32x4 s0 = (f32x4){0.f, 0.f, 0.f, 0.f};
        f32x4 s1 = (f32x4){0.f, 0.f, 0.f, 0.f};
#pragma unroll
        for (int kf = 0; kf < 8; ++kf) {
            int pc = (kf * 4 + quad) ^ swz;
            s16x8 b0 = *(const s16x8*)(&Kt[cur][m16 * 256 + pc * 8]);
            s16x8 b1 = *(const s16x8*)(&Kt[cur][(16 + m16) * 256 + pc * 8]);
            s0 = mfma16(b0, qf[kf], s0);   // swapped: D[key][q]
            s1 = mfma16(b1, qf[kf], s1);
        }
#pragma unroll
        for (int r = 0; r < 4; ++r) {
            lacc += __expf(s0[r]) + __expf(s1[r]);
            racc += fmaxf(s0[r], 0.f) + fmaxf(s1[r], 0.f);
        }
    }
    lacc += __shfl_xor(lacc, 16); lacc += __shfl_xor(lacc, 32);
    racc += __shfl_xor(racc, 16); racc += __shfl_xor(racc, 32);
    if (quad == 0) {
        int row = split * N_Q + qbase + wave * 16 + m16;
        Lp[row] = lacc;
        Rp[row] = racc;
    }
}

// ---------------- K3: pass B — single-path PV with in-register P ----------------
// P' = 0.1*relu(S) + exp(S)*invL  (invL from pass A). Swapped QK puts P lane-local;
// 8 UNCONDITIONAL shfls + per-lane selects redistribute to the PV A-frag
// (divergent-ternary shfl was the round-3 bug: convergent intrinsic under
// divergent exec reads inactive source lanes). V from LDS (transposed tile).
__global__ __launch_bounds__(256, 2) void k_pv(const u16* __restrict__ XQ,
                                               const u16* __restrict__ YK,
                                               const u16* __restrict__ YVt,
                                               const float* __restrict__ Lp,
                                               u16* __restrict__ Ob,
                                               int msPerSplit) {
    __shared__ u16 Kt[2][32 * 256];  // K tile, XOR-swizzled chunks, dbuf (32 KB)
    __shared__ u16 Vt[2][256 * 32];  // V^T tile [p][key], linear, dbuf (32 KB)

    const int tid = threadIdx.x;
    const int wave = tid >> 6, lane = tid & 63;
    const int quad = lane >> 4, m16 = lane & 15;
    const int split = blockIdx.y;
    const int qbase = blockIdx.x * 64;
    const int key_begin = split * msPerSplit;
    const int iters = msPerSplit / BK;
    const int swz = m16 & 7;

    // invL for this lane's q-row (sum of 4 pass-A splits)
    float Ltot = 0.f;
#pragma unroll
    for (int s = 0; s < 4; ++s)
        Ltot += Lp[(size_t)s * N_Q + qbase + wave * 16 + m16];
    const float invL = 1.f / Ltot;

    s16x8 qf[8];
    const u16* qp = XQ + (size_t)(qbase + wave * 16 + m16) * DSIN;
#pragma unroll
    for (int kf = 0; kf < 8; ++kf)
        qf[kf] = *(const s16x8*)(qp + kf * 32 + quad * 8);

    f32x4 acc[16];
#pragma unroll
    for (int pt = 0; pt < 16; ++pt) acc[pt] = (f32x4){0.f, 0.f, 0.f, 0.f};

    auto stage = [&](int key0, int buf) {
#pragma unroll
        for (int c = 0; c < 4; ++c) {             // K: swizzled source chunks
            int l = (wave * 4 + c) * 64 + lane;
            int r = l >> 5;
            int sc = (l & 31) ^ (r & 7);
            gload_lds16(YK + (size_t)(key0 + r) * DSIN + sc * 8,
                        &Kt[buf][(size_t)(wave * 4 + c) * 512]);
        }
#pragma unroll
        for (int c = 0; c < 4; ++c) {             // Vt: linear [p][key] rows of 64B
            int l = (wave * 4 + c) * 64 + lane;   // chunk: p = l>>2, cc = l&3
            gload_lds16(YVt + (size_t)(l >> 2) * MCTX + key0 + (l & 3) * 8,
                        &Vt[buf][(size_t)(wave * 4 + c) * 512]);
        }
    };
    stage(key_begin, 0);

    const int srcA = ((quad & 1) << 5) + m16;  // P-shuffle source lanes
    const int srcB = srcA + 16;

    for (int it = 0; it < iters; ++it) {
        const int cur = it & 1;
        __syncthreads();   // DMA(cur) landed (syncthreads drains vmcnt); bufs safe
        if (it + 1 < iters) stage(key_begin + (it + 1) * BK, cur ^ 1);

        // QK swapped: lane holds S[key=quad*4+r][q=m16] (s0), [16+quad*4+r] (s1)
        f32x4 s0 = (f32x4){0.f, 0.f, 0.f, 0.f};
        f32x4 s1 = (f32x4){0.f, 0.f, 0.f, 0.f};
#pragma unroll
        for (int kf = 0; kf < 8; ++kf) {
            int pc = (kf * 4 + quad) ^ swz;
            s16x8 b0 = *(const s16x8*)(&Kt[cur][m16 * 256 + pc * 8]);
            s16x8 b1 = *(const s16x8*)(&Kt[cur][(16 + m16) * 256 + pc * 8]);
            s0 = mfma16(b0, qf[kf], s0);
            s1 = mfma16(b1, qf[kf], s1);
        }
        // combined P' in f32, pack to bf16 pairs (keys {4q+2w, 4q+2w+1})
        float pp[8];
#pragma unroll
        for (int r = 0; r < 4; ++r) {
            pp[r]     = 0.1f * fmaxf(s0[r], 0.f) + __expf(s0[r]) * invL;
            pp[4 + r] = 0.1f * fmaxf(s1[r], 0.f) + __expf(s1[r]) * invL;
        }
        unsigned w0 = pack2bf(pp[0], pp[1]);   // keys {4q+0, 4q+1}
        unsigned w1 = pack2bf(pp[2], pp[3]);   // keys {4q+2, 4q+3}
        unsigned w2 = pack2bf(pp[4], pp[5]);   // keys {16+4q+0, 16+4q+1}
        unsigned w3 = pack2bf(pp[6], pp[7]);   // keys {16+4q+2, 16+4q+3}
        // redistribute: dest lane (quad,m16) A-frag word w = keys {8*quad+2w,+1}.
        // ALL shfls unconditional (convergent), selection via per-lane cndmask.
        int a0 = __shfl((int)w0, srcA), a1 = __shfl((int)w1, srcA);
        int a2 = __shfl((int)w2, srcA), a3 = __shfl((int)w3, srcA);
        int b0_ = __shfl((int)w0, srcB), b1_ = __shfl((int)w1, srcB);
        int b2_ = __shfl((int)w2, srcB), b3_ = __shfl((int)w3, srcB);
        const bool loq = (quad < 2);
        union { unsigned u[4]; s16x8 v; } pa;
        pa.u[0] = (unsigned)(loq ? a0 : a2);
        pa.u[1] = (unsigned)(loq ? a1 : a3);
        pa.u[2] = (unsigned)(loq ? b0_ : b2_);
        pa.u[3] = (unsigned)(loq ? b1_ : b3_);

        // PV: 16 independent MFMAs, B-frags from transposed V tile (conflict-free)
#pragma unroll
        for (int pt = 0; pt < 16; ++pt) {
            s16x8 vf = *(const s16x8*)(&Vt[cur][(pt * 16 + m16) * 32 + quad * 8]);
            acc[pt] = mfma16(pa.v, vf, acc[pt]);
        }
    }

    // epilogue: bf16 partial out (D-normalization applied in k_comb)
    size_t ob = ((size_t)split * N_Q + qbase) * PDIM;
#pragma unroll
    for (int pt = 0; pt < 16; ++pt)
#pragma unroll
        for (int r = 0; r < 4; ++r)
            Ob[ob + (size_t)(wave * 16 + quad * 4 + r) * PDIM + pt * 16 + m16] =
                f2bf(acc[pt][r]);
}

// ---------------- K4: combine 2 splits, apply 1/D ----------------
__global__ void k_comb(const u16* __restrict__ Ob, const float* __restrict__ Rp,
                       float* __restrict__ out) {
    int row = blockIdx.x * 8 + (threadIdx.x >> 5);
    int col = (threadIdx.x & 31) * 8;
    size_t idx = (size_t)row * PDIM + col;
    const size_t NP = (size_t)N_Q * PDIM;
    float Rs = 0.f;
#pragma unroll
    for (int s = 0; s < 4; ++s) Rs += Rp[(size_t)s * N_Q + row];
    float invD = 1.f / (1.f + 0.1f * Rs);
    s16x8 e0 = *(const s16x8*)(Ob + idx);
    s16x8 e1 = *(const s16x8*)(Ob + NP + idx);
    float4 o0, o1;
    o0.x = (bf2f((u16)e0[0]) + bf2f((u16)e1[0])) * invD;
    o0.y = (bf2f((u16)e0[1]) + bf2f((u16)e1[1])) * invD;
    o0.z = (bf2f((u16)e0[2]) + bf2f((u16)e1[2])) * invD;
    o0.w = (bf2f((u16)e0[3]) + bf2f((u16)e1[3])) * invD;
    o1.x = (bf2f((u16)e0[4]) + bf2f((u16)e1[4])) * invD;
    o1.y = (bf2f((u16)e0[5]) + bf2f((u16)e1[5])) * invD;
    o1.z = (bf2f((u16)e0[6]) + bf2f((u16)e1[6])) * invD;
    o1.w = (bf2f((u16)e0[7]) + bf2f((u16)e1[7])) * invD;
    *(float4*)(out + idx) = o0;
    *(float4*)(out + idx + 4) = o1;
}

extern "C" void kernel_launch(void* const* d_in, const int* in_sizes, int n_in,
                              void* d_out, int out_size, void* d_ws, size_t ws_size,
                              hipStream_t stream) {
    const float* x  = (const float*)d_in[0];
    const float* y  = (const float*)d_in[1];
    const float* Wq = (const float*)d_in[2];
    const float* Wk = (const float*)d_in[3];
    const float* Wv = (const float*)d_in[4];
    float* out = (float*)d_out;

    char* ws = (char*)d_ws;
    size_t off = 0;
    auto take = [&](size_t bytes) -> char* {
        char* p = ws + off;
        off += (bytes + 255) & ~(size_t)255;
        return p;
    };
    u16*   XQ  = (u16*)take((size_t)N_Q * PDIM * 2);
    u16*   WtH = (u16*)take((size_t)PDIM * DSIN * 2);
    u16*   WtL = (u16*)take((size_t)PDIM * DSIN * 2);
    u16*   YK  = (u16*)take((size_t)MCTX * PDIM * 2);
    u16*   YVt = (u16*)take((size_t)PDIM * MCTX * 2);
    u16*   Ob  = (u16*)take((size_t)2 * N_Q * PDIM * 2);   // 2 key-splits, bf16
    float* Lpart = (float*)take((size_t)4 * N_Q * 4);      // 4 key-splits (pass A)
    float* Rpart = (float*)take((size_t)4 * N_Q * 4);

    hipLaunchKernelGGL(k_prep, dim3(PDIM + MCTX/32), dim3(256), 0, stream,
                       Wq, WtH, WtL, y, Wk, Wv, YK, YVt);
    hipLaunchKernelGGL(k_xq,   dim3(N_Q/32), dim3(256), 0, stream, x, WtH, WtL, XQ);
    hipLaunchKernelGGL(k_lr,   dim3(N_Q/64, 4), dim3(256), 0, stream,
                       XQ, YK, Lpart, Rpart, MCTX / 4);
    hipLaunchKernelGGL(k_pv,   dim3(N_Q/64, 2), dim3(256), 0, stream,
                       XQ, YK, YVt, Lpart, Ob, MCTX / 2);
    hipLaunchKernelGGL(k_comb, dim3(N_Q/8), dim3(256), 0, stream, Ob, Rpart, out);
}

// Round 5
// 240.820 us; speedup vs baseline: 1.1215x; 1.1215x over previous
//
#include <hip/hip_runtime.h>
#include <hip/hip_bf16.h>

#define N_Q   16384
#define MCTX  4096
#define DSIN  256
#define YDIM  7
#define PDIM  256   // SPROJ
#define BK    32

typedef __attribute__((ext_vector_type(8))) short s16x8;   // 8 bf16 (4 VGPRs)
typedef __attribute__((ext_vector_type(4))) float f32x4;   // MFMA C/D frag
typedef unsigned short u16;

static __device__ __forceinline__ u16 f2bf(float f) {
    union { float f; unsigned u; } v; v.f = f;
    unsigned r = v.u + 0x7fffu + ((v.u >> 16) & 1u);  // RNE
    return (u16)(r >> 16);
}
static __device__ __forceinline__ float bf2f(u16 h) {
    union { unsigned u; float f; } v; v.u = ((unsigned)h) << 16;
    return v.f;
}
static __device__ __forceinline__ f32x4 mfma16(s16x8 a, s16x8 b, f32x4 c) {
    return __builtin_amdgcn_mfma_f32_16x16x32_bf16(a, b, c, 0, 0, 0);
}
// async 16B global->LDS DMA (dst = wave-uniform base + lane*16)
static __device__ __forceinline__ void gload_lds16(const u16* g, u16* l) {
    __builtin_amdgcn_global_load_lds(
        (const __attribute__((address_space(1))) unsigned int*)(g),
        (__attribute__((address_space(3))) unsigned int*)(l), 16, 0, 0);
}

// ---------------- K_prep: (a) Wq transpose + hi/lo split, (b) YK + YVb ----------------
__global__ void k_prep(const float* __restrict__ Wq, u16* __restrict__ WtH,
                       u16* __restrict__ WtL, const float* __restrict__ y,
                       const float* __restrict__ Wk, const float* __restrict__ Wv,
                       u16* __restrict__ YK, u16* __restrict__ YVb) {
    if (blockIdx.x < PDIM) {
        int n = blockIdx.x;   // 0..PDIM-1
        int k = threadIdx.x;  // 0..DSIN-1
        float w = Wq[(size_t)k * PDIM + n];
        u16 h = f2bf(w);
        WtH[(size_t)n * DSIN + k] = h;
        WtL[(size_t)n * DSIN + k] = f2bf(w - bf2f(h));
    } else {
        // YK scaled 1/16 row-major [key][p]; YVb coalesced PV-frag layout [kb][p][32]
        int kb = blockIdx.x - PDIM;  // key block (32 keys)
        int p  = threadIdx.x;        // proj
        float wk[YDIM], wv[YDIM];
#pragma unroll
        for (int j = 0; j < YDIM; ++j) {
            wk[j] = Wk[(size_t)j * PDIM + p];
            wv[j] = Wv[(size_t)j * PDIM + p];
        }
        u16 vbuf[32];
#pragma unroll
        for (int m = 0; m < 32; ++m) {
            int key = kb * 32 + m;
            float ak = 0.f, av = 0.f;
#pragma unroll
            for (int j = 0; j < YDIM; ++j) {
                float yy = y[(size_t)key * YDIM + j];
                ak += yy * wk[j];
                av += yy * wv[j];
            }
            YK[(size_t)key * PDIM + p] = f2bf(ak * 0.0625f);  // fold 1/sqrt(256)
            vbuf[m] = f2bf(av);
        }
        s16x8* dst = (s16x8*)(YVb + ((size_t)kb * PDIM + p) * 32);
#pragma unroll
        for (int c = 0; c < 4; ++c) dst[c] = ((s16x8*)vbuf)[c];
    }
}

// ---------------- K1: XQ = x @ Wq, hi/lo split; 32-row tiles, 2 blocks/CU ----------------
__global__ __launch_bounds__(256, 2) void k_xq(const float* __restrict__ x,
                                               const u16* __restrict__ WtH,
                                               const u16* __restrict__ WtL,
                                               u16* __restrict__ XQ) {
    __shared__ u16 xH[32 * 256];  // XOR-swizzled 16B chunks: phys c = c ^ (row&7)
    __shared__ u16 xL[32 * 256];
    const int tid = threadIdx.x;
    const int rowg0 = blockIdx.x * 32;
#pragma unroll
    for (int i = 0; i < 4; ++i) {
        int row = (tid >> 5) + i * 8;
        int c32 = tid & 31;
        const float* px = x + (size_t)(rowg0 + row) * DSIN + c32 * 8;
        float4 a = *(const float4*)px;
        float4 b = *(const float4*)(px + 4);
        float vals[8] = {a.x, a.y, a.z, a.w, b.x, b.y, b.z, b.w};
        s16x8 h, l;
#pragma unroll
        for (int j = 0; j < 8; ++j) {
            u16 hh = f2bf(vals[j]);
            h[j] = (short)hh;
            l[j] = (short)f2bf(vals[j] - bf2f(hh));
        }
        int pc = c32 ^ (row & 7);
        *(s16x8*)(xH + row * 256 + pc * 8) = h;
        *(s16x8*)(xL + row * 256 + pc * 8) = l;
    }
    __syncthreads();

    const int wave = tid >> 6, lane = tid & 63;
    const int quad = lane >> 4, m16 = lane & 15;
    const int rh = wave & 1, ph = wave >> 1;
    const int rowl = rh * 16 + m16;
    const int swz = rowl & 7;
    s16x8 ah[8], al[8];
#pragma unroll
    for (int kf = 0; kf < 8; ++kf) {
        int pc = (kf * 4 + quad) ^ swz;
        ah[kf] = *(const s16x8*)(xH + rowl * 256 + pc * 8);
        al[kf] = *(const s16x8*)(xL + rowl * 256 + pc * 8);
    }
#pragma unroll
    for (int ptl = 0; ptl < 8; ++ptl) {
        int pt = ph * 8 + ptl;
        f32x4 acc = (f32x4){0.f, 0.f, 0.f, 0.f};
#pragma unroll
        for (int kf = 0; kf < 8; ++kf) {
            size_t idx = (size_t)(pt * 16 + m16) * DSIN + kf * 32 + quad * 8;
            s16x8 bh = *(const s16x8*)(WtH + idx);
            s16x8 bl = *(const s16x8*)(WtL + idx);
            acc = mfma16(ah[kf], bh, acc);
            acc = mfma16(al[kf], bh, acc);
            acc = mfma16(ah[kf], bl, acc);
        }
#pragma unroll
        for (int r = 0; r < 4; ++r)
            XQ[(size_t)(rowg0 + rh * 16 + quad * 4 + r) * PDIM + pt * 16 + m16] =
                f2bf(acc[r]);
    }
}

// ---------------- K3: fused attention, cooperative-S + cross-tile pipeline ----------------
// Round-0 structure (64q x 256p, 4 waves; wave w: S-quarter rows w*16..+16, PV p-slice
// [64w,64w+64)) restructured to ONE barrier per iteration:
//   body(t): barrier; vf(t-1) loads; stage K(t+1) DMA; QK(t); PV(t-1); exp(t)->Pe/Pr[t&1]
// Kt/Pe/Pr all double-buffered. Hazards: every same-buffer WAR/RAW pair is separated by
// the top-of-body barrier (checked per buffer). vf issued BEFORE the DMA so the compiler's
// vmcnt wait for vf leaves the 4 newer DMA ops in flight (round-0's ordering trick).
// QK(t) and PV(t-1) are independent MFMA chains -> ILP; exp(t) VALU overlaps PV's MFMAs.
__global__ __launch_bounds__(256, 2) void k_attn(const u16* __restrict__ XQ,
                                                 const u16* __restrict__ YK,
                                                 const u16* __restrict__ YVb,
                                                 u16* __restrict__ accE,
                                                 u16* __restrict__ accR,
                                                 float* __restrict__ lsum,
                                                 float* __restrict__ rsum,
                                                 int msPerSplit) {
    __shared__ u16 Kt[2][32 * 256];  // 32 keys x 256 d, XOR-swizzled chunks, dbuf (32KB)
    __shared__ u16 Pe[2][64 * 40];   // 64 q x 32 keys, pad->40, dbuf (10.2KB)
    __shared__ u16 Pr[2][64 * 40];

    const int tid = threadIdx.x;
    const int wave = tid >> 6, lane = tid & 63;
    const int quad = lane >> 4, m16 = lane & 15;
    const int split = blockIdx.y;
    const int qbase = blockIdx.x * 64;
    const int key_begin = split * msPerSplit;
    const int iters = msPerSplit / BK;
    const int pslice = wave * 64;
    const int swz = m16 & 7;

    // Q A-frags for this wave's 16 S-rows
    s16x8 qf[8];
    const u16* qp = XQ + (size_t)(qbase + wave * 16 + m16) * DSIN;
#pragma unroll
    for (int kf = 0; kf < 8; ++kf)
        qf[kf] = *(const s16x8*)(qp + kf * 32 + quad * 8);

    f32x4 aE[4][4], aR[4][4];
#pragma unroll
    for (int g = 0; g < 4; ++g)
#pragma unroll
        for (int t = 0; t < 4; ++t) {
            aE[g][t] = (f32x4){0.f, 0.f, 0.f, 0.f};
            aR[g][t] = (f32x4){0.f, 0.f, 0.f, 0.f};
        }
    float lacc[4] = {0.f, 0.f, 0.f, 0.f}, racc[4] = {0.f, 0.f, 0.f, 0.f};

    // stage K tile via DMA into buffer `buf`; source chunk XOR-permuted (phys swizzled)
    auto stage = [&](int key0, int buf) {
#pragma unroll
        for (int c = 0; c < 4; ++c) {
            int l = (wave * 4 + c) * 64 + lane;   // phys chunk 0..1023
            int r = l >> 5;                        // key row 0..31
            int sc = (l & 31) ^ (r & 7);           // source chunk in row
            gload_lds16(YK + (size_t)(key0 + r) * DSIN + sc * 8,
                        &Kt[buf][(size_t)(wave * 4 + c) * 512]);
        }
    };
    // PV of tile `pt_idx` (buffer b) with already-loaded vf
    auto pv = [&](int b, const s16x8* vf) {
#pragma unroll
        for (int g = 0; g < 4; ++g) {
            s16x8 pa = *(const s16x8*)(&Pe[b][(g * 16 + m16) * 40 + quad * 8]);
            s16x8 pb = *(const s16x8*)(&Pr[b][(g * 16 + m16) * 40 + quad * 8]);
#pragma unroll
            for (int t = 0; t < 4; ++t) {
                aE[g][t] = mfma16(pa, vf[t], aE[g][t]);
                aR[g][t] = mfma16(pb, vf[t], aR[g][t]);
            }
        }
    };

    stage(key_begin, 0);   // prologue: tile 0 -> buf 0

    for (int it = 0; it < iters; ++it) {
        const int key0 = key_begin + it * BK;
        const int cur = it & 1;
        __syncthreads();   // K(it) landed; Pe/Pr(it-1) visible; all dbuf WARs resolved

        // vf for PV(it-1): issue FIRST so its vmcnt wait leaves the DMA below in flight
        s16x8 vf[4];
        if (it > 0) {
            const u16* vb = YVb + (size_t)(((key0 - BK) >> 5) * PDIM) * 32;
#pragma unroll
            for (int t = 0; t < 4; ++t)
                vf[t] = *(const s16x8*)(vb + (size_t)(pslice + t * 16 + m16) * 32 + quad * 8);
        }
        if (it + 1 < iters) stage(key0 + BK, cur ^ 1);  // async prefetch K(it+1)

        // QK(it): S-quarter rows wave*16+quad*4+r, keys m16 / 16+m16
        f32x4 s0 = (f32x4){0.f, 0.f, 0.f, 0.f};
        f32x4 s1 = (f32x4){0.f, 0.f, 0.f, 0.f};
        __builtin_amdgcn_s_setprio(1);
#pragma unroll
        for (int kf = 0; kf < 8; ++kf) {
            int pc = (kf * 4 + quad) ^ swz;        // (16+m16)&7 == m16&7
            s16x8 b0 = *(const s16x8*)(&Kt[cur][m16 * 256 + pc * 8]);
            s16x8 b1 = *(const s16x8*)(&Kt[cur][(16 + m16) * 256 + pc * 8]);
            s0 = mfma16(qf[kf], b0, s0);
            s1 = mfma16(qf[kf], b1, s1);
        }
        // PV(it-1): independent of QK(it) -> interleaves on the MFMA pipe
        if (it > 0) pv(cur ^ 1, vf);
        __builtin_amdgcn_s_setprio(0);

        // exp/relu(it) in C-layout; per-lane partial row sums; bf16 -> Pe/Pr[cur]
#pragma unroll
        for (int r = 0; r < 4; ++r) {
            float e0 = __expf(s0[r]), e1 = __expf(s1[r]);
            float rl0 = fmaxf(s0[r], 0.f), rl1 = fmaxf(s1[r], 0.f);
            lacc[r] += e0 + e1;
            racc[r] += rl0 + rl1;
            int row = wave * 16 + quad * 4 + r;
            Pe[cur][row * 40 + m16]      = f2bf(e0);
            Pe[cur][row * 40 + 16 + m16] = f2bf(e1);
            Pr[cur][row * 40 + m16]      = f2bf(rl0);
            Pr[cur][row * 40 + 16 + m16] = f2bf(rl1);
        }
    }

    // drain: PV of the final tile
    __syncthreads();
    {
        const int keyL = key_begin + (iters - 1) * BK;
        const int bL = (iters - 1) & 1;
        s16x8 vf[4];
        const u16* vb = YVb + (size_t)((keyL >> 5) * PDIM) * 32;
#pragma unroll
        for (int t = 0; t < 4; ++t)
            vf[t] = *(const s16x8*)(vb + (size_t)(pslice + t * 16 + m16) * 32 + quad * 8);
        pv(bL, vf);
    }

    // epilogue: bf16 partial O and row sums
    size_t ob = ((size_t)split * N_Q + qbase) * PDIM;
#pragma unroll
    for (int g = 0; g < 4; ++g)
#pragma unroll
        for (int t = 0; t < 4; ++t)
#pragma unroll
            for (int r = 0; r < 4; ++r) {
                size_t o = ob + (size_t)(g * 16 + quad * 4 + r) * PDIM + pslice + t * 16 + m16;
                accE[o] = f2bf(aE[g][t][r]);
                accR[o] = f2bf(aR[g][t][r]);
            }
#pragma unroll
    for (int r = 0; r < 4; ++r) {
        lacc[r] += __shfl_xor(lacc[r], 1);
        lacc[r] += __shfl_xor(lacc[r], 2);
        lacc[r] += __shfl_xor(lacc[r], 4);
        lacc[r] += __shfl_xor(lacc[r], 8);
        racc[r] += __shfl_xor(racc[r], 1);
        racc[r] += __shfl_xor(racc[r], 2);
        racc[r] += __shfl_xor(racc[r], 4);
        racc[r] += __shfl_xor(racc[r], 8);
    }
    if (m16 < 4) {
        float lv = (m16 == 0) ? lacc[0] : (m16 == 1) ? lacc[1] : (m16 == 2) ? lacc[2] : lacc[3];
        float rv = (m16 == 0) ? racc[0] : (m16 == 1) ? racc[1] : (m16 == 2) ? racc[2] : racc[3];
        int row = split * N_Q + qbase + wave * 16 + quad * 4 + m16;
        lsum[row] = lv;
        rsum[row] = rv;
    }
}

// ---------------- K4: combine splits + normalization (bf16 partials in) ----------------
__global__ void k_comb(const u16* __restrict__ accE, const u16* __restrict__ accR,
                       const float* __restrict__ lsum, const float* __restrict__ rsum,
                       float* __restrict__ out, int nsplit) {
    int row = blockIdx.x * 8 + (threadIdx.x >> 5);
    int col = (threadIdx.x & 31) * 8;
    size_t idx = (size_t)row * PDIM + col;
    const size_t NP = (size_t)N_Q * PDIM;
    float E[8] = {0.f, 0.f, 0.f, 0.f, 0.f, 0.f, 0.f, 0.f};
    float R[8] = {0.f, 0.f, 0.f, 0.f, 0.f, 0.f, 0.f, 0.f};
    float L = 0.f, Rs = 0.f;
    for (int s = 0; s < nsplit; ++s) {
        s16x8 e = *(const s16x8*)(accE + s * NP + idx);
        s16x8 r = *(const s16x8*)(accR + s * NP + idx);
#pragma unroll
        for (int j = 0; j < 8; ++j) {
            E[j] += bf2f((u16)e[j]);
            R[j] += bf2f((u16)r[j]);
        }
        L  += lsum[(size_t)s * N_Q + row];
        Rs += rsum[(size_t)s * N_Q + row];
    }
    float invL = 1.f / L, invD = 1.f / (1.f + 0.1f * Rs);
    float4 o0, o1;
    o0.x = (0.1f * R[0] + E[0] * invL) * invD;
    o0.y = (0.1f * R[1] + E[1] * invL) * invD;
    o0.z = (0.1f * R[2] + E[2] * invL) * invD;
    o0.w = (0.1f * R[3] + E[3] * invL) * invD;
    o1.x = (0.1f * R[4] + E[4] * invL) * invD;
    o1.y = (0.1f * R[5] + E[5] * invL) * invD;
    o1.z = (0.1f * R[6] + E[6] * invL) * invD;
    o1.w = (0.1f * R[7] + E[7] * invL) * invD;
    *(float4*)(out + idx) = o0;
    *(float4*)(out + idx + 4) = o1;
}

extern "C" void kernel_launch(void* const* d_in, const int* in_sizes, int n_in,
                              void* d_out, int out_size, void* d_ws, size_t ws_size,
                              hipStream_t stream) {
    const float* x  = (const float*)d_in[0];
    const float* y  = (const float*)d_in[1];
    const float* Wq = (const float*)d_in[2];
    const float* Wk = (const float*)d_in[3];
    const float* Wv = (const float*)d_in[4];
    float* out = (float*)d_out;

    char* ws = (char*)d_ws;
    size_t off = 0;
    auto take = [&](size_t bytes) -> char* {
        char* p = ws + off;
        off += (bytes + 255) & ~(size_t)255;
        return p;
    };
    u16* XQ  = (u16*)take((size_t)N_Q * PDIM * 2);
    u16* WtH = (u16*)take((size_t)PDIM * DSIN * 2);
    u16* WtL = (u16*)take((size_t)PDIM * DSIN * 2);
    u16* YK  = (u16*)take((size_t)MCTX * PDIM * 2);
    u16* YVb = (u16*)take((size_t)MCTX * PDIM * 2);

    size_t perSplit = (size_t)N_Q * PDIM * 2 * 2 + (size_t)N_Q * 4 * 2 + 1024;
    int nsplit = (ws_size >= off + 2 * perSplit + 4096) ? 2 : 1;

    u16*   accE = (u16*)take((size_t)nsplit * N_Q * PDIM * 2);
    u16*   accR = (u16*)take((size_t)nsplit * N_Q * PDIM * 2);
    float* lsum = (float*)take((size_t)nsplit * N_Q * 4);
    float* rsum = (float*)take((size_t)nsplit * N_Q * 4);

    hipLaunchKernelGGL(k_prep, dim3(PDIM + MCTX/32), dim3(256), 0, stream,
                       Wq, WtH, WtL, y, Wk, Wv, YK, YVb);
    hipLaunchKernelGGL(k_xq,   dim3(N_Q/32), dim3(256), 0, stream, x, WtH, WtL, XQ);
    hipLaunchKernelGGL(k_attn, dim3(N_Q/64, nsplit), dim3(256), 0, stream,
                       XQ, YK, YVb, accE, accR, lsum, rsum, MCTX / nsplit);
    hipLaunchKernelGGL(k_comb, dim3(N_Q/8), dim3(256), 0, stream,
                       accE, accR, lsum, rsum, out, nsplit);
}

// Round 8
// 228.117 us; speedup vs baseline: 1.1839x; 1.0557x over previous
//
#include <hip/hip_runtime.h>
#include <hip/hip_bf16.h>

#define N_Q   16384
#define MCTX  4096
#define DSIN  256
#define YDIM  7
#define PDIM  256   // SPROJ
#define BK    32

typedef __attribute__((ext_vector_type(8))) short s16x8;   // 8 bf16 (4 VGPRs)
typedef __attribute__((ext_vector_type(4))) float f32x4;   // MFMA C/D frag
typedef unsigned short u16;

static __device__ __forceinline__ u16 f2bf(float f) {
    union { float f; unsigned u; } v; v.f = f;
    unsigned r = v.u + 0x7fffu + ((v.u >> 16) & 1u);  // RNE
    return (u16)(r >> 16);
}
static __device__ __forceinline__ float bf2f(u16 h) {
    union { unsigned u; float f; } v; v.u = ((unsigned)h) << 16;
    return v.f;
}
static __device__ __forceinline__ f32x4 mfma16(s16x8 a, s16x8 b, f32x4 c) {
    return __builtin_amdgcn_mfma_f32_16x16x32_bf16(a, b, c, 0, 0, 0);
}
// async 16B global->LDS DMA (dst = wave-uniform base + lane*16)
static __device__ __forceinline__ void gload_lds16(const u16* g, u16* l) {
    __builtin_amdgcn_global_load_lds(
        (const __attribute__((address_space(1))) unsigned int*)(g),
        (__attribute__((address_space(3))) unsigned int*)(l), 16, 0, 0);
}

// ---------------- K_prep: (a) Wq transpose + hi/lo split, (b) YK + YVb ----------------
__global__ void k_prep(const float* __restrict__ Wq, u16* __restrict__ WtH,
                       u16* __restrict__ WtL, const float* __restrict__ y,
                       const float* __restrict__ Wk, const float* __restrict__ Wv,
                       u16* __restrict__ YK, u16* __restrict__ YVb) {
    if (blockIdx.x < PDIM) {
        int n = blockIdx.x;   // 0..PDIM-1
        int k = threadIdx.x;  // 0..DSIN-1
        float w = Wq[(size_t)k * PDIM + n];
        u16 h = f2bf(w);
        WtH[(size_t)n * DSIN + k] = h;
        WtL[(size_t)n * DSIN + k] = f2bf(w - bf2f(h));
    } else {
        // YK scaled 1/16 row-major [key][p]; YVb coalesced PV-frag layout [kb][p][32]
        int kb = blockIdx.x - PDIM;  // key block (32 keys)
        int p  = threadIdx.x;        // proj
        float wk[YDIM], wv[YDIM];
#pragma unroll
        for (int j = 0; j < YDIM; ++j) {
            wk[j] = Wk[(size_t)j * PDIM + p];
            wv[j] = Wv[(size_t)j * PDIM + p];
        }
        u16 vbuf[32];
#pragma unroll
        for (int m = 0; m < 32; ++m) {
            int key = kb * 32 + m;
            float ak = 0.f, av = 0.f;
#pragma unroll
            for (int j = 0; j < YDIM; ++j) {
                float yy = y[(size_t)key * YDIM + j];
                ak += yy * wk[j];
                av += yy * wv[j];
            }
            YK[(size_t)key * PDIM + p] = f2bf(ak * 0.0625f);  // fold 1/sqrt(256)
            vbuf[m] = f2bf(av);
        }
        s16x8* dst = (s16x8*)(YVb + ((size_t)kb * PDIM + p) * 32);
#pragma unroll
        for (int c = 0; c < 4; ++c) dst[c] = ((s16x8*)vbuf)[c];
    }
}

// ---------------- K1: XQ = x @ Wq, hi/lo split; 32-row tiles, 2 blocks/CU ----------------
__global__ __launch_bounds__(256, 2) void k_xq(const float* __restrict__ x,
                                               const u16* __restrict__ WtH,
                                               const u16* __restrict__ WtL,
                                               u16* __restrict__ XQ) {
    __shared__ u16 xH[32 * 256];  // XOR-swizzled 16B chunks: phys c = c ^ (row&7)
    __shared__ u16 xL[32 * 256];
    const int tid = threadIdx.x;
    const int rowg0 = blockIdx.x * 32;
#pragma unroll
    for (int i = 0; i < 4; ++i) {
        int row = (tid >> 5) + i * 8;
        int c32 = tid & 31;
        const float* px = x + (size_t)(rowg0 + row) * DSIN + c32 * 8;
        float4 a = *(const float4*)px;
        float4 b = *(const float4*)(px + 4);
        float vals[8] = {a.x, a.y, a.z, a.w, b.x, b.y, b.z, b.w};
        s16x8 h, l;
#pragma unroll
        for (int j = 0; j < 8; ++j) {
            u16 hh = f2bf(vals[j]);
            h[j] = (short)hh;
            l[j] = (short)f2bf(vals[j] - bf2f(hh));
        }
        int pc = c32 ^ (row & 7);
        *(s16x8*)(xH + row * 256 + pc * 8) = h;
        *(s16x8*)(xL + row * 256 + pc * 8) = l;
    }
    __syncthreads();

    const int wave = tid >> 6, lane = tid & 63;
    const int quad = lane >> 4, m16 = lane & 15;
    const int rh = wave & 1, ph = wave >> 1;
    const int rowl = rh * 16 + m16;
    const int swz = rowl & 7;
    s16x8 ah[8], al[8];
#pragma unroll
    for (int kf = 0; kf < 8; ++kf) {
        int pc = (kf * 4 + quad) ^ swz;
        ah[kf] = *(const s16x8*)(xH + rowl * 256 + pc * 8);
        al[kf] = *(const s16x8*)(xL + rowl * 256 + pc * 8);
    }
#pragma unroll
    for (int ptl = 0; ptl < 8; ++ptl) {
        int pt = ph * 8 + ptl;
        f32x4 acc = (f32x4){0.f, 0.f, 0.f, 0.f};
#pragma unroll
        for (int kf = 0; kf < 8; ++kf) {
            size_t idx = (size_t)(pt * 16 + m16) * DSIN + kf * 32 + quad * 8;
            s16x8 bh = *(const s16x8*)(WtH + idx);
            s16x8 bl = *(const s16x8*)(WtL + idx);
            acc = mfma16(ah[kf], bh, acc);
            acc = mfma16(al[kf], bh, acc);
            acc = mfma16(ah[kf], bl, acc);
        }
#pragma unroll
        for (int r = 0; r < 4; ++r)
            XQ[(size_t)(rowg0 + rh * 16 + quad * 4 + r) * PDIM + pt * 16 + m16] =
                f2bf(acc[r]);
    }
}

// ---------------- K3: fused attention — round-0 structure (129 µs), bf16 partial out ----
// Block: 64 q x 256 p, 4 waves. Wave w: computes S-quarter (rows w*16..+16) via QK,
// exp/relu in C-layout -> bf16 Pe/Pr LDS; PV over p-slice [64w,64w+64) using all Pe/Pr.
// K: global_load_lds (XOR-swizzled source). V: registers from coalesced YVb.
__global__ __launch_bounds__(256, 2) void k_attn(const u16* __restrict__ XQ,
                                                 const u16* __restrict__ YK,
                                                 const u16* __restrict__ YVb,
                                                 u16* __restrict__ accE,
                                                 u16* __restrict__ accR,
                                                 float* __restrict__ lsum,
                                                 float* __restrict__ rsum,
                                                 int msPerSplit) {
    __shared__ u16 Kt[32 * 256];   // 32 keys x 256 d, XOR-swizzled chunks
    __shared__ u16 Pe[64 * 40];    // 64 q x 32 keys, pad->40 (2-way max)
    __shared__ u16 Pr[64 * 40];

    const int tid = threadIdx.x;
    const int wave = tid >> 6, lane = tid & 63;
    const int quad = lane >> 4, m16 = lane & 15;
    const int split = blockIdx.y;
    const int qbase = blockIdx.x * 64;
    const int key_begin = split * msPerSplit;
    const int iters = msPerSplit / BK;
    const int pslice = wave * 64;
    const int swz = m16 & 7;

    // Q A-frags for this wave's 16 S-rows
    s16x8 qf[8];
    const u16* qp = XQ + (size_t)(qbase + wave * 16 + m16) * DSIN;
#pragma unroll
    for (int kf = 0; kf < 8; ++kf)
        qf[kf] = *(const s16x8*)(qp + kf * 32 + quad * 8);

    f32x4 aE[4][4], aR[4][4];
#pragma unroll
    for (int g = 0; g < 4; ++g)
#pragma unroll
        for (int t = 0; t < 4; ++t) {
            aE[g][t] = (f32x4){0.f, 0.f, 0.f, 0.f};
            aR[g][t] = (f32x4){0.f, 0.f, 0.f, 0.f};
        }
    float lacc[4] = {0.f, 0.f, 0.f, 0.f}, racc[4] = {0.f, 0.f, 0.f, 0.f};

    // stage K tile for key0 via DMA; source chunk XOR-permuted so phys layout is swizzled
    auto stage = [&](int key0) {
#pragma unroll
        for (int c = 0; c < 4; ++c) {
            int l = (wave * 4 + c) * 64 + lane;   // phys chunk 0..1023
            int r = l >> 5;                        // key row 0..31
            int sc = (l & 31) ^ (r & 7);           // source chunk in row
            gload_lds16(YK + (size_t)(key0 + r) * DSIN + sc * 8,
                        Kt + (size_t)(wave * 4 + c) * 512);
        }
    };
    stage(key_begin);

    for (int it = 0; it < iters; ++it) {
        const int key0 = key_begin + it * BK;
        __syncthreads();   // Kt(it) visible (vmcnt0 + barrier)

        // QK: S-quarter rows wave*16+quad*4+r, keys m16 / 16+m16
        f32x4 s0 = (f32x4){0.f, 0.f, 0.f, 0.f};
        f32x4 s1 = (f32x4){0.f, 0.f, 0.f, 0.f};
        __builtin_amdgcn_s_setprio(1);
#pragma unroll
        for (int kf = 0; kf < 8; ++kf) {
            int pc = (kf * 4 + quad) ^ swz;        // (16+m16)&7 == m16&7
            s16x8 b0 = *(const s16x8*)(Kt + m16 * 256 + pc * 8);
            s16x8 b1 = *(const s16x8*)(Kt + (16 + m16) * 256 + pc * 8);
            s0 = mfma16(qf[kf], b0, s0);
            s1 = mfma16(qf[kf], b1, s1);
        }
        __builtin_amdgcn_s_setprio(0);
        // exp/relu in C-layout; per-lane partial row sums; bf16 -> Pe/Pr
#pragma unroll
        for (int r = 0; r < 4; ++r) {
            float e0 = __expf(s0[r]), e1 = __expf(s1[r]);
            float rl0 = fmaxf(s0[r], 0.f), rl1 = fmaxf(s1[r], 0.f);
            lacc[r] += e0 + e1;
            racc[r] += rl0 + rl1;
            int row = wave * 16 + quad * 4 + r;
            Pe[row * 40 + m16]      = f2bf(e0);
            Pe[row * 40 + 16 + m16] = f2bf(e1);
            Pr[row * 40 + m16]      = f2bf(rl0);
            Pr[row * 40 + 16 + m16] = f2bf(rl1);
        }
        __syncthreads();   // Pe/Pr visible; Kt free to overwrite

        // V-frags first (so their vmcnt wait doesn't drain the DMA below)
        s16x8 vf[4];
        const u16* vb = YVb + (size_t)((key0 >> 5) * PDIM) * 32;
#pragma unroll
        for (int t = 0; t < 4; ++t)
            vf[t] = *(const s16x8*)(vb + (size_t)(pslice + t * 16 + m16) * 32 + quad * 8);

        if (it + 1 < iters) stage(key0 + BK);  // async prefetch of next K tile

        // PV: dual path, V-frag reused 8x, Pe/Pr A-frags from LDS
        __builtin_amdgcn_s_setprio(1);
#pragma unroll
        for (int g = 0; g < 4; ++g) {
            s16x8 pa = *(const s16x8*)(Pe + (g * 16 + m16) * 40 + quad * 8);
            s16x8 pb = *(const s16x8*)(Pr + (g * 16 + m16) * 40 + quad * 8);
#pragma unroll
            for (int t = 0; t < 4; ++t) {
                aE[g][t] = mfma16(pa, vf[t], aE[g][t]);
                aR[g][t] = mfma16(pb, vf[t], aR[g][t]);
            }
        }
        __builtin_amdgcn_s_setprio(0);
    }

    // epilogue: bf16 partial O and row sums
    size_t ob = ((size_t)split * N_Q + qbase) * PDIM;
#pragma unroll
    for (int g = 0; g < 4; ++g)
#pragma unroll
        for (int t = 0; t < 4; ++t)
#pragma unroll
            for (int r = 0; r < 4; ++r) {
                size_t o = ob + (size_t)(g * 16 + quad * 4 + r) * PDIM + pslice + t * 16 + m16;
                accE[o] = f2bf(aE[g][t][r]);
                accR[o] = f2bf(aR[g][t][r]);
            }
#pragma unroll
    for (int r = 0; r < 4; ++r) {
        lacc[r] += __shfl_xor(lacc[r], 1);
        lacc[r] += __shfl_xor(lacc[r], 2);
        lacc[r] += __shfl_xor(lacc[r], 4);
        lacc[r] += __shfl_xor(lacc[r], 8);
        racc[r] += __shfl_xor(racc[r], 1);
        racc[r] += __shfl_xor(racc[r], 2);
        racc[r] += __shfl_xor(racc[r], 4);
        racc[r] += __shfl_xor(racc[r], 8);
    }
    if (m16 < 4) {
        float lv = (m16 == 0) ? lacc[0] : (m16 == 1) ? lacc[1] : (m16 == 2) ? lacc[2] : lacc[3];
        float rv = (m16 == 0) ? racc[0] : (m16 == 1) ? racc[1] : (m16 == 2) ? racc[2] : racc[3];
        int row = split * N_Q + qbase + wave * 16 + quad * 4 + m16;
        lsum[row] = lv;
        rsum[row] = rv;
    }
}

// ---------------- K4: combine splits + normalization (bf16 partials in) ----------------
__global__ void k_comb(const u16* __restrict__ accE, const u16* __restrict__ accR,
                       const float* __restrict__ lsum, const float* __restrict__ rsum,
                       float* __restrict__ out, int nsplit) {
    int row = blockIdx.x * 8 + (threadIdx.x >> 5);
    int col = (threadIdx.x & 31) * 8;
    size_t idx = (size_t)row * PDIM + col;
    const size_t NP = (size_t)N_Q * PDIM;
    float E[8] = {0.f, 0.f, 0.f, 0.f, 0.f, 0.f, 0.f, 0.f};
    float R[8] = {0.f, 0.f, 0.f, 0.f, 0.f, 0.f, 0.f, 0.f};
    float L = 0.f, Rs = 0.f;
    for (int s = 0; s < nsplit; ++s) {
        s16x8 e = *(const s16x8*)(accE + s * NP + idx);
        s16x8 r = *(const s16x8*)(accR + s * NP + idx);
#pragma unroll
        for (int j = 0; j < 8; ++j) {
            E[j] += bf2f((u16)e[j]);
            R[j] += bf2f((u16)r[j]);
        }
        L  += lsum[(size_t)s * N_Q + row];
        Rs += rsum[(size_t)s * N_Q + row];
    }
    float invL = 1.f / L, invD = 1.f / (1.f + 0.1f * Rs);
    float4 o0, o1;
    o0.x = (0.1f * R[0] + E[0] * invL) * invD;
    o0.y = (0.1f * R[1] + E[1] * invL) * invD;
    o0.z = (0.1f * R[2] + E[2] * invL) * invD;
    o0.w = (0.1f * R[3] + E[3] * invL) * invD;
    o1.x = (0.1f * R[4] + E[4] * invL) * invD;
    o1.y = (0.1f * R[5] + E[5] * invL) * invD;
    o1.z = (0.1f * R[6] + E[6] * invL) * invD;
    o1.w = (0.1f * R[7] + E[7] * invL) * invD;
    *(float4*)(out + idx) = o0;
    *(float4*)(out + idx + 4) = o1;
}

extern "C" void kernel_launch(void* const* d_in, const int* in_sizes, int n_in,
                              void* d_out, int out_size, void* d_ws, size_t ws_size,
                              hipStream_t stream) {
    const float* x  = (const float*)d_in[0];
    const float* y  = (const float*)d_in[1];
    const float* Wq = (const float*)d_in[2];
    const float* Wk = (const float*)d_in[3];
    const float* Wv = (const float*)d_in[4];
    float* out = (float*)d_out;

    char* ws = (char*)d_ws;
    size_t off = 0;
    auto take = [&](size_t bytes) -> char* {
        char* p = ws + off;
        off += (bytes + 255) & ~(size_t)255;
        return p;
    };
    u16* XQ  = (u16*)take((size_t)N_Q * PDIM * 2);
    u16* WtH = (u16*)take((size_t)PDIM * DSIN * 2);
    u16* WtL = (u16*)take((size_t)PDIM * DSIN * 2);
    u16* YK  = (u16*)take((size_t)MCTX * PDIM * 2);
    u16* YVb = (u16*)take((size_t)MCTX * PDIM * 2);

    size_t perSplit = (size_t)N_Q * PDIM * 2 * 2 + (size_t)N_Q * 4 * 2 + 1024;
    int nsplit = (ws_size >= off + 2 * perSplit + 4096) ? 2 : 1;

    u16*   accE = (u16*)take((size_t)nsplit * N_Q * PDIM * 2);
    u16*   accR = (u16*)take((size_t)nsplit * N_Q * PDIM * 2);
    float* lsum = (float*)take((size_t)nsplit * N_Q * 4);
    float* rsum = (float*)take((size_t)nsplit * N_Q * 4);

    hipLaunchKernelGGL(k_prep, dim3(PDIM + MCTX/32), dim3(256), 0, stream,
                       Wq, WtH, WtL, y, Wk, Wv, YK, YVb);
    hipLaunchKernelGGL(k_xq,   dim3(N_Q/32), dim3(256), 0, stream, x, WtH, WtL, XQ);
    hipLaunchKernelGGL(k_attn, dim3(N_Q/64, nsplit), dim3(256), 0, stream,
                       XQ, YK, YVb, accE, accR, lsum, rsum, MCTX / nsplit);
    hipLaunchKernelGGL(k_comb, dim3(N_Q/8), dim3(256), 0, stream,
                       accE, accR, lsum, rsum, out, nsplit);
}